// Round 1
// baseline (271.070 us; speedup 1.0000x reference)
//
#include <hip/hip_runtime.h>

// OKRRouter: raw = x @ gate_W^T ; wm = x @ secret ; safe = raw >= max-1.5 ;
// top2 over (safe ? wm : -1e9) ; softmax of raw gathered at top2.
// Fused single kernel: tall-skinny fp32 GEMM (M=16384, N=128, K=2048) + router epilogue.

#define TM   32     // tokens per block
#define KC   64     // K chunk staged in LDS
#define NOUT 128    // 64 raw logits + 64 watermark biases
#define DDIM 2048
#define NEXP 64
#define RS   129    // res row stride (conflict-free epilogue reads)

__global__ __launch_bounds__(128, 2)
void okr_router_kernel(const float* __restrict__ x,       // [ntok][2048]
                       const float* __restrict__ gateW,   // [64][2048]
                       const float* __restrict__ secret,  // [2048][64]
                       float* __restrict__ out,           // [ntok*2 weights][ntok*2 experts]
                       int ntok)
{
    __shared__ float xs[KC][TM];     // 8 KB,  xs[k][t]
    __shared__ float bs[KC][NOUT];   // 32 KB, bs[k][o]  (o<64: gate^T, o>=64: secret)

    const int tid  = threadIdx.x;    // 0..127
    const int tok0 = blockIdx.x * TM;
    const int tx   = tid & 31;       // output group -> outputs tx*4 .. tx*4+3
    const int ty   = tid >> 5;       // token group  -> tokens  ty*8 .. ty*8+7

    float acc[8][4];
    #pragma unroll
    for (int i = 0; i < 8; ++i)
        #pragma unroll
        for (int j = 0; j < 4; ++j) acc[i][j] = 0.0f;

    for (int kc = 0; kc < DDIM; kc += KC) {
        // ---- stage x tile: 32 tokens x 64 k = 512 float4, 4 per thread (coalesced) ----
        #pragma unroll
        for (int jj = 0; jj < 4; ++jj) {
            const int f = tid + 128 * jj;        // 0..511
            const int t = f >> 4;                // 0..31
            const int q = f & 15;                // float4 slot in row
            const float4 v = *reinterpret_cast<const float4*>(
                &x[(size_t)(tok0 + t) * DDIM + kc + q * 4]);
            xs[q*4+0][t] = v.x; xs[q*4+1][t] = v.y;
            xs[q*4+2][t] = v.z; xs[q*4+3][t] = v.w;
        }
        // ---- stage gate^T: 64 e x 64 k = 1024 float4, 8 per thread (coalesced read, scatter write) ----
        #pragma unroll
        for (int jj = 0; jj < 8; ++jj) {
            const int f = tid + 128 * jj;        // 0..1023
            const int e = f >> 4;                // 0..63
            const int q = f & 15;
            const float4 v = *reinterpret_cast<const float4*>(
                &gateW[(size_t)e * DDIM + kc + q * 4]);
            bs[q*4+0][e] = v.x; bs[q*4+1][e] = v.y;
            bs[q*4+2][e] = v.z; bs[q*4+3][e] = v.w;
        }
        // ---- stage secret: 64 k x 64 e, layout already [k][e] -> direct float4 copy ----
        #pragma unroll
        for (int jj = 0; jj < 8; ++jj) {
            const int f  = tid + 128 * jj;       // 0..1023
            const int k  = f >> 4;               // 0..63
            const int e4 = (f & 15) * 4;
            const float4 v = *reinterpret_cast<const float4*>(
                &secret[(size_t)(kc + k) * NEXP + e4]);
            *reinterpret_cast<float4*>(&bs[k][64 + e4]) = v;
        }
        __syncthreads();

        // ---- compute: per kk, 2 broadcast A-reads + 1 B-read, 32 FMAs ----
        #pragma unroll 8
        for (int kk = 0; kk < KC; ++kk) {
            const float4 a0 = *reinterpret_cast<const float4*>(&xs[kk][ty * 8]);
            const float4 a1 = *reinterpret_cast<const float4*>(&xs[kk][ty * 8 + 4]);
            const float4 b  = *reinterpret_cast<const float4*>(&bs[kk][tx * 4]);
            const float av[8] = {a0.x, a0.y, a0.z, a0.w, a1.x, a1.y, a1.z, a1.w};
            const float bv[4] = {b.x, b.y, b.z, b.w};
            #pragma unroll
            for (int i = 0; i < 8; ++i)
                #pragma unroll
                for (int j = 0; j < 4; ++j)
                    acc[i][j] = fmaf(av[i], bv[j], acc[i][j]);
        }
        __syncthreads();
    }

    // ---- epilogue: dump accumulators to LDS (overlay bs), then per-token router ----
    float* res = &bs[0][0];   // needs 32*129 = 4128 floats <= 8192 available
    #pragma unroll
    for (int i = 0; i < 8; ++i)
        #pragma unroll
        for (int j = 0; j < 4; ++j)
            res[(ty * 8 + i) * RS + tx * 4 + j] = acc[i][j];
    __syncthreads();

    if (tid < TM) {
        const int t = tid;
        const float* r = &res[t * RS];   // r[0..63] = raw, r[64..127] = wm

        float rawmax = -3.4e38f;
        #pragma unroll 8
        for (int e = 0; e < NEXP; ++e) rawmax = fmaxf(rawmax, r[e]);
        const float thr = rawmax - 1.5f;

        // top-2 of modified scores; strict > keeps lowest index on ties (jax.lax.top_k)
        float v1 = -3.4e38f, v2 = -3.4e38f;
        int e1 = 0, e2 = 0;
        for (int e = 0; e < NEXP; ++e) {
            const float raw = r[e];
            const float m = (raw >= thr) ? r[64 + e] : -1000000000.0f;
            if (m > v1)      { v2 = v1; e2 = e1; v1 = m; e1 = e; }
            else if (m > v2) { v2 = m;  e2 = e; }
        }

        const float l1 = r[e1], l2 = r[e2];
        const float mm = fmaxf(l1, l2);
        const float x1 = expf(l1 - mm), x2 = expf(l2 - mm);
        const float inv = 1.0f / (x1 + x2);

        const size_t gt = (size_t)tok0 + t;
        out[gt * 2 + 0] = x1 * inv;
        out[gt * 2 + 1] = x2 * inv;
        out[(size_t)ntok * 2 + gt * 2 + 0] = (float)e1;
        out[(size_t)ntok * 2 + gt * 2 + 1] = (float)e2;
    }
}

extern "C" void kernel_launch(void* const* d_in, const int* in_sizes, int n_in,
                              void* d_out, int out_size, void* d_ws, size_t ws_size,
                              hipStream_t stream) {
    const float* x      = (const float*)d_in[0];
    const float* gateW  = (const float*)d_in[1];
    const float* secret = (const float*)d_in[2];
    float* out = (float*)d_out;

    const int ntok = in_sizes[0] / DDIM;    // 4*4096 = 16384
    const int grid = ntok / TM;             // 512 blocks

    okr_router_kernel<<<grid, 128, 0, stream>>>(x, gateW, secret, out, ntok);
}

// Round 3
// 98.883 us; speedup vs baseline: 2.7413x; 2.7413x over previous
//
#include <hip/hip_runtime.h>
#include <stdint.h>

// OKRRouter via split-bf16 MFMA (hi/lo 2-way split, 3 product terms) +
// exact fp32 recompute fallback for boundary-margin tokens.
// K1: convert gate_W^T | secret -> bf16 hi/lo MFMA-fragment-linear layout in ws.
// K2: zero-LDS split-K GEMM (M=16384, N=128, K=2048), fp32 partials -> ws.
// K3: reduce partials + router (mask/top-2/softmax) with margin-guarded
//     fp32 recompute of raw/wm for rare near-tie tokens.

#define DDIM 2048
#define NEXP 64
#define NCOL 128
#define BM   128
#define NEG_INF   -1000000000.0f
#define MARGIN_RAW 0.01f
#define MARGIN_WM  0.05f

typedef __attribute__((ext_vector_type(8))) short bf16x8;
typedef __attribute__((ext_vector_type(4))) float f32x4;

union BFrag { bf16x8 v; uint32_t w[4]; uint4 q; };

// split 8 fp32 into bf16 hi (RNE) and bf16 lo (RNE of exact fp32 residual)
__device__ inline void split8(const float* a, bf16x8* hi, bf16x8* lo) {
    BFrag h, l;
    #pragma unroll
    for (int p = 0; p < 4; ++p) {
        const uint32_t u0 = __float_as_uint(a[2*p]);
        const uint32_t u1 = __float_as_uint(a[2*p+1]);
        const uint32_t h0 = (u0 + 0x7FFFu + ((u0 >> 16) & 1u)) >> 16;
        const uint32_t h1 = (u1 + 0x7FFFu + ((u1 >> 16) & 1u)) >> 16;
        const float r0 = a[2*p]   - __uint_as_float(h0 << 16);   // exact
        const float r1 = a[2*p+1] - __uint_as_float(h1 << 16);
        const uint32_t v0 = __float_as_uint(r0);
        const uint32_t v1 = __float_as_uint(r1);
        const uint32_t l0 = (v0 + 0x7FFFu + ((v0 >> 16) & 1u)) >> 16;
        const uint32_t l1 = (v1 + 0x7FFFu + ((v1 >> 16) & 1u)) >> 16;
        h.w[p] = h0 | (h1 << 16);
        l.w[p] = l0 | (l1 << 16);
    }
    *hi = h.v; *lo = l.v;
}

// ---- K1: B' fragments. frag f = kstep*8+s is 128 uint4: 64 lanes hi, 64 lanes lo.
// lane l holds B[kstep*32 + (l>>4)*8 + j][s*16 + (l&15)], j=0..7
__global__ void prep_b(const float* __restrict__ gateW, const float* __restrict__ secret,
                       uint4* __restrict__ wsB) {
    const int kstep = blockIdx.x;            // 0..63
    const int s = threadIdx.x >> 6;          // 0..7
    const int l = threadIdx.x & 63;
    const int col = s * 16 + (l & 15);
    const int kb  = kstep * 32 + (l >> 4) * 8;
    float v[8];
    if (col < NEXP) {
        #pragma unroll
        for (int j = 0; j < 8; ++j) v[j] = gateW[(size_t)col * DDIM + kb + j];
    } else {
        #pragma unroll
        for (int j = 0; j < 8; ++j) v[j] = secret[(size_t)(kb + j) * NEXP + (col - NEXP)];
    }
    bf16x8 hi, lo; split8(v, &hi, &lo);
    const size_t base = (size_t)(kstep * 8 + s) * 128 + l;
    BFrag t;
    t.v = hi; wsB[base]      = t.q;
    t.v = lo; wsB[base + 64] = t.q;
}

// ---- K2: split-K GEMM, no LDS. grid = (ntok/BM)*KSPLIT, 256 thr ----
template <int KSPLIT>
__global__ __launch_bounds__(256, 2)
void gemm_split(const float* __restrict__ x, const uint4* __restrict__ wsB,
                float* __restrict__ wsP, int ntok) {
    const int KQ  = DDIM / KSPLIT;
    const int NKS = KQ / 32;
    const int bx = blockIdx.x;
    const int q  = bx & (KSPLIT - 1);
    const int mb = bx / KSPLIT;
    const int w  = threadIdx.x >> 6;
    const int l  = threadIdx.x & 63;
    const int rl = l & 15;
    const int kg = l >> 4;
    const int rowb = mb * BM + w * 32;

    f32x4 acc[2][8];
    #pragma unroll
    for (int i = 0; i < 2; ++i)
        #pragma unroll
        for (int j = 0; j < 8; ++j) acc[i][j] = (f32x4){0.f, 0.f, 0.f, 0.f};

    const float* xr0 = x + (size_t)(rowb + rl) * DDIM + q * KQ + kg * 8;
    const float* xr1 = xr0 + (size_t)16 * DDIM;
    // FIX: fragment base for K-quarter q is q*NKS*8 fragments (was q*NKS)
    const uint4* bp  = wsB + (size_t)(q * NKS * 8) * 128 + l;

    for (int ts = 0; ts < NKS; ++ts) {
        bf16x8 bh[8], bl[8];
        #pragma unroll
        for (int s = 0; s < 8; ++s) {
            BFrag t;
            t.q = bp[(size_t)(ts * 8 + s) * 128];      bh[s] = t.v;
            t.q = bp[(size_t)(ts * 8 + s) * 128 + 64]; bl[s] = t.v;
        }
        const float4 a0 = *reinterpret_cast<const float4*>(xr0 + ts * 32);
        const float4 a1 = *reinterpret_cast<const float4*>(xr0 + ts * 32 + 4);
        const float4 a2 = *reinterpret_cast<const float4*>(xr1 + ts * 32);
        const float4 a3 = *reinterpret_cast<const float4*>(xr1 + ts * 32 + 4);
        const float v0[8] = {a0.x, a0.y, a0.z, a0.w, a1.x, a1.y, a1.z, a1.w};
        const float v1[8] = {a2.x, a2.y, a2.z, a2.w, a3.x, a3.y, a3.z, a3.w};
        bf16x8 ah0, al0, ah1, al1;
        split8(v0, &ah0, &al0);
        split8(v1, &ah1, &al1);

        #pragma unroll
        for (int s = 0; s < 8; ++s) {
            acc[0][s] = __builtin_amdgcn_mfma_f32_16x16x32_bf16(ah0, bh[s], acc[0][s], 0, 0, 0);
            acc[0][s] = __builtin_amdgcn_mfma_f32_16x16x32_bf16(ah0, bl[s], acc[0][s], 0, 0, 0);
            acc[0][s] = __builtin_amdgcn_mfma_f32_16x16x32_bf16(al0, bh[s], acc[0][s], 0, 0, 0);
            acc[1][s] = __builtin_amdgcn_mfma_f32_16x16x32_bf16(ah1, bh[s], acc[1][s], 0, 0, 0);
            acc[1][s] = __builtin_amdgcn_mfma_f32_16x16x32_bf16(ah1, bl[s], acc[1][s], 0, 0, 0);
            acc[1][s] = __builtin_amdgcn_mfma_f32_16x16x32_bf16(al1, bh[s], acc[1][s], 0, 0, 0);
        }
    }

    // C/D layout: row = (l>>4)*4 + reg, col = l&15
    const size_t MN = (size_t)ntok * NCOL;
    #pragma unroll
    for (int m = 0; m < 2; ++m) {
        const int tokb = rowb + m * 16 + kg * 4;
        #pragma unroll
        for (int s = 0; s < 8; ++s)
            #pragma unroll
            for (int r = 0; r < 4; ++r)
                wsP[(size_t)q * MN + (size_t)(tokb + r) * NCOL + s * 16 + rl] = acc[m][s][r];
    }
}

// argmax with lowest-index tie-break across 64 lanes
__device__ inline void wave_argmax(float& bv, int& bi) {
    #pragma unroll
    for (int off = 32; off; off >>= 1) {
        const float ov = __shfl_xor(bv, off);
        const int   oi = __shfl_xor(bi, off);
        if (ov > bv || (ov == bv && oi < bi)) { bv = ov; bi = oi; }
    }
}

// ---- K3: reduce split-K + router with margin-guarded fp32 recompute ----
template <int KSPLIT>
__global__ void router_k(const float* __restrict__ wsP,
                         const float* __restrict__ x,
                         const float* __restrict__ gateW,
                         const float* __restrict__ secret,
                         float* __restrict__ out, int ntok) {
    const int t = blockIdx.x * 4 + (threadIdx.x >> 6);
    const int e = threadIdx.x & 63;
    const size_t MN = (size_t)ntok * NCOL;

    float raw = 0.f, wm = 0.f;
    #pragma unroll
    for (int q = 0; q < KSPLIT; ++q) {
        raw += wsP[(size_t)q * MN + (size_t)t * NCOL + e];
        wm  += wsP[(size_t)q * MN + (size_t)t * NCOL + NEXP + e];
    }

    float rmax = raw;
    #pragma unroll
    for (int off = 32; off; off >>= 1) rmax = fmaxf(rmax, __shfl_xor(rmax, off));

    // guard 1: safe-mask boundary margin -> exact fp32 raw recompute
    if (__any(fabsf(raw - (rmax - 1.5f)) < MARGIN_RAW)) {
        float s = 0.f;
        const float4* xr = reinterpret_cast<const float4*>(x + (size_t)t * DDIM);
        const float4* wr = reinterpret_cast<const float4*>(gateW + (size_t)e * DDIM);
        for (int k = 0; k < DDIM / 4; ++k) {
            const float4 a = xr[k], b = wr[k];
            s = fmaf(a.x, b.x, s); s = fmaf(a.y, b.y, s);
            s = fmaf(a.z, b.z, s); s = fmaf(a.w, b.w, s);
        }
        raw = s;
        rmax = raw;
        #pragma unroll
        for (int off = 32; off; off >>= 1) rmax = fmaxf(rmax, __shfl_xor(rmax, off));
    }

    const bool safe = (raw >= rmax - 1.5f);
    float m = safe ? wm : NEG_INF;

    // top-3 (value desc, lowest index on ties)
    float v1 = m; int e1 = e;
    wave_argmax(v1, e1);
    float v2 = (e == e1) ? -3.0e38f : m; int e2 = e;
    wave_argmax(v2, e2);
    float v3 = (e == e1 || e == e2) ? -3.0e38f : m; int e3 = e;
    wave_argmax(v3, e3);

    // guard 2: close wm ordering among non-masked candidates -> exact fp32 wm
    const bool wmRisk = (v2 > NEG_INF + 1.0f && v1 - v2 < MARGIN_WM) ||
                        (v3 > NEG_INF + 1.0f && v2 - v3 < MARGIN_WM);
    if (__any(wmRisk)) {
        float s = 0.f;
        const float* xr = x + (size_t)t * DDIM;
        for (int k = 0; k < DDIM; k += 4) {
            s = fmaf(xr[k],     secret[(size_t)(k)     * NEXP + e], s);
            s = fmaf(xr[k + 1], secret[(size_t)(k + 1) * NEXP + e], s);
            s = fmaf(xr[k + 2], secret[(size_t)(k + 2) * NEXP + e], s);
            s = fmaf(xr[k + 3], secret[(size_t)(k + 3) * NEXP + e], s);
        }
        m = safe ? s : NEG_INF;
        v1 = m; e1 = e;  wave_argmax(v1, e1);
        v2 = (e == e1) ? -3.0e38f : m; e2 = e;  wave_argmax(v2, e2);
    }

    const float l1 = __shfl(raw, e1);
    const float l2 = __shfl(raw, e2);

    if (e == 0) {
        const float mm = fmaxf(l1, l2);
        const float x1 = expf(l1 - mm), x2 = expf(l2 - mm);
        const float inv = 1.0f / (x1 + x2);
        out[(size_t)t * 2 + 0] = x1 * inv;
        out[(size_t)t * 2 + 1] = x2 * inv;
        out[(size_t)2 * ntok + t * 2 + 0] = (float)e1;
        out[(size_t)2 * ntok + t * 2 + 1] = (float)e2;
    }
}

extern "C" void kernel_launch(void* const* d_in, const int* in_sizes, int n_in,
                              void* d_out, int out_size, void* d_ws, size_t ws_size,
                              hipStream_t stream) {
    const float* x      = (const float*)d_in[0];
    const float* gateW  = (const float*)d_in[1];
    const float* secret = (const float*)d_in[2];
    float* out = (float*)d_out;

    const int ntok = in_sizes[0] / DDIM;       // 16384
    uint4* wsB = (uint4*)d_ws;                 // 1 MB fragments
    float* wsP = (float*)((char*)d_ws + (2u << 20));
    const size_t MN4 = (size_t)ntok * NCOL * 4;

    prep_b<<<64, 512, 0, stream>>>(gateW, secret, wsB);

    if (ws_size >= (2u << 20) + 4 * MN4) {
        gemm_split<4><<<(ntok / BM) * 4, 256, 0, stream>>>(x, wsB, wsP, ntok);
        router_k<4><<<ntok / 4, 256, 0, stream>>>(wsP, x, gateW, secret, out, ntok);
    } else if (ws_size >= (2u << 20) + 2 * MN4) {
        gemm_split<2><<<(ntok / BM) * 2, 256, 0, stream>>>(x, wsB, wsP, ntok);
        router_k<2><<<ntok / 4, 256, 0, stream>>>(wsP, x, gateW, secret, out, ntok);
    } else {
        gemm_split<1><<<(ntok / BM), 256, 0, stream>>>(x, wsB, wsP, ntok);
        router_k<1><<<ntok / 4, 256, 0, stream>>>(wsP, x, gateW, secret, out, ntok);
    }
}